// Round 1
// baseline (959.200 us; speedup 1.0000x reference)
//
#include <hip/hip_runtime.h>
#include <hip/hip_bf16.h>
#include <math.h>

#define NHEAD 16
#define DK 64
#define SEQL 2048
#define NBATCH 2
#define DMODEL 1024
#define MROWS 4096   // NBATCH*SEQL

typedef __attribute__((ext_vector_type(4))) float floatx4;
typedef __attribute__((ext_vector_type(8))) short short8;
typedef __attribute__((ext_vector_type(4))) short short4v;

__device__ __forceinline__ short f2bf(float f) {
    __hip_bfloat16 h = __float2bfloat16(f);
    return *reinterpret_cast<short*>(&h);
}

__device__ __forceinline__ void gll16(const void* g, void* l) {
    __builtin_amdgcn_global_load_lds(
        (const __attribute__((address_space(1))) void*)g,
        (__attribute__((address_space(3))) void*)l, 16, 0, 0);
}

// ---------------- fp32 -> bf16 convert (vectorized x4) ----------------
__global__ void cvt_bf16(const float* __restrict__ in, short* __restrict__ out, int n4) {
    int i = blockIdx.x * 256 + threadIdx.x;
    if (i < n4) {
        float4 f = ((const float4*)in)[i];
        short4v v;
        v.x = f2bf(f.x); v.y = f2bf(f.y); v.z = f2bf(f.z); v.w = f2bf(f.w);
        ((short4v*)out)[i] = v;
    }
}

// ---------------- GEMM: C[m,n] = sum_k A[m,k]*W[n,k] + bias[n] ----------------
// A: [MROWS, 1024] bf16 row-major; W: [1024, 1024] bf16 row-major (n,k)
// MODE 0: store bf16 at [((b*16+h)*2048+l)*64 + d]   (per-head q/k layout)
// MODE 1: store bf16 at [((b*16+h)*64+d)*2048 + l]   (transposed v layout)
// MODE 2: store fp32 at [m*1024 + n]
template<int MODE>
__global__ __launch_bounds__(256, 2)
void gemm_bt(const short* __restrict__ A, const short* __restrict__ W,
             const float* __restrict__ bias, void* __restrict__ Out) {
    __shared__ __align__(16) short As[128 * 32];
    __shared__ __align__(16) short Bs[128 * 32];
    const int t = threadIdx.x;
    const int lane = t & 63;
    const int w = t >> 6;
    const int wr = w >> 1, wc = w & 1;
    const int quad = lane >> 4;
    const int l16 = lane & 15;
    const int bm = blockIdx.y * 128;
    const int bn = blockIdx.x * 128;

    floatx4 acc[4][4];
#pragma unroll
    for (int i = 0; i < 4; ++i)
#pragma unroll
        for (int j = 0; j < 4; ++j) acc[i][j] = (floatx4){0.f, 0.f, 0.f, 0.f};

    for (int k0 = 0; k0 < 1024; k0 += 32) {
        __syncthreads();
#pragma unroll
        for (int i = 0; i < 2; ++i) {
            int c = i * 256 + t;
            int row = c >> 2, kk = (c & 3) * 8;
            gll16(A + (size_t)(bm + row) * 1024 + k0 + kk, (char*)As + c * 16);
            gll16(W + (size_t)(bn + row) * 1024 + k0 + kk, (char*)Bs + c * 16);
        }
        __syncthreads();
        short8 af[4], bfr[4];
#pragma unroll
        for (int ms = 0; ms < 4; ++ms)
            af[ms] = *(const short8*)&As[(wr * 64 + ms * 16 + l16) * 32 + quad * 8];
#pragma unroll
        for (int ns = 0; ns < 4; ++ns)
            bfr[ns] = *(const short8*)&Bs[(wc * 64 + ns * 16 + l16) * 32 + quad * 8];
#pragma unroll
        for (int ms = 0; ms < 4; ++ms)
#pragma unroll
            for (int ns = 0; ns < 4; ++ns)
                acc[ms][ns] = __builtin_amdgcn_mfma_f32_16x16x32_bf16(
                    af[ms], bfr[ns], acc[ms][ns], 0, 0, 0);
    }

#pragma unroll
    for (int ms = 0; ms < 4; ++ms) {
#pragma unroll
        for (int ns = 0; ns < 4; ++ns) {
            int n = bn + wc * 64 + ns * 16 + l16;
            float bv = bias[n];
#pragma unroll
            for (int r = 0; r < 4; ++r) {
                int m = bm + wr * 64 + ms * 16 + quad * 4 + r;
                float v = acc[ms][ns][r] + bv;
                if (MODE == 2) {
                    ((float*)Out)[(size_t)m * 1024 + n] = v;
                } else {
                    int b = m >> 11, l = m & 2047;
                    int h = n >> 6, d = n & 63;
                    short* o = (short*)Out;
                    if (MODE == 0)
                        o[(((size_t)(b * 16 + h) * 2048 + l) * 64) + d] = f2bf(v);
                    else
                        o[(((size_t)(b * 16 + h) * 64 + d) * 2048) + l] = f2bf(v);
                }
            }
        }
    }
}

// ---------------- attention: per (q-tile 64, bh) block ----------------
// Qh,Kh: [BH, L, 64] bf16 ; Vt: [BH, 64, L] bf16
// P (fp32) -> attnW [BH, L, L]; O (bf16) -> Ows [B*L, 1024]
// Barrier-free: K/V are L2-resident (256KB each per bh, shared by 32 blocks);
// fragments loaded directly from global. No max-tracking in softmax
// (|scores| <~ 8 << 88, exp(s)/sum(exp(s)) is exact in fp32 here).
#define EXPSCALE 0.18033688f   // 0.125 * log2(e); exp(s/8) == exp2(s*EXPSCALE)
__global__ __launch_bounds__(256, 3)
void attn_kernel(const short* __restrict__ Qh, const short* __restrict__ Kh,
                 const short* __restrict__ Vt, float* __restrict__ P,
                 short* __restrict__ Ows) {
    __shared__ __align__(16) short Ps[2 * 64 * 32];   // wave-local regions (rows w*16..w*16+15)

    const int t = threadIdx.x;
    const int lane = t & 63;
    const int w = t >> 6;
    const int quad = lane >> 4;
    const int l16 = lane & 15;
    const int qt = blockIdx.x;   // 0..31
    const int bh = blockIdx.y;   // 0..31
    const size_t qkBase = (size_t)bh * SEQL * DK;

    // Q fragments, direct from global (one row per lane, both 32-k halves)
    short8 aq[2];
    {
        const short* qrow = Qh + qkBase + (size_t)(qt * 64 + w * 16 + l16) * 64;
        aq[0] = *(const short8*)(qrow + quad * 8);
        aq[1] = *(const short8*)(qrow + 32 + quad * 8);
    }

    // ---- pass 1: per-lane partial exp-sums (no cross-lane ops in loop) ----
    float psum[4] = {0.f, 0.f, 0.f, 0.f};
#pragma unroll 2
    for (int kt = 0; kt < 32; ++kt) {
        const short* kb_base = Kh + qkBase + (size_t)kt * 64 * 64;
        short8 kb[2][4];
#pragma unroll
        for (int ks = 0; ks < 2; ++ks)
#pragma unroll
            for (int ns = 0; ns < 4; ++ns)
                kb[ks][ns] = *(const short8*)(kb_base + (size_t)(ns * 16 + l16) * 64 + ks * 32 + quad * 8);
        floatx4 s[4];
#pragma unroll
        for (int ns = 0; ns < 4; ++ns) s[ns] = (floatx4){0.f, 0.f, 0.f, 0.f};
#pragma unroll
        for (int ks = 0; ks < 2; ++ks)
#pragma unroll
            for (int ns = 0; ns < 4; ++ns)
                s[ns] = __builtin_amdgcn_mfma_f32_16x16x32_bf16(aq[ks], kb[ks][ns], s[ns], 0, 0, 0);
#pragma unroll
        for (int ns = 0; ns < 4; ++ns)
#pragma unroll
            for (int r = 0; r < 4; ++r)
                psum[r] += exp2f(s[ns][r] * EXPSCALE);
    }
    // single reduce across the 16-lane column group (rows are per (w,quad,r))
#pragma unroll
    for (int off = 1; off < 16; off <<= 1)
#pragma unroll
        for (int r = 0; r < 4; ++r)
            psum[r] += __shfl_xor(psum[r], off, 64);
    float inv_l[4];
#pragma unroll
    for (int r = 0; r < 4; ++r) inv_l[r] = 1.f / psum[r];

    floatx4 oacc[4];
#pragma unroll
    for (int i = 0; i < 4; ++i) oacc[i] = (floatx4){0.f, 0.f, 0.f, 0.f};

    // ---- pass 2: recompute S, write P (non-temporal), accumulate O ----
    for (int kt = 0; kt < 32; ++kt) {
        const short* kb_base = Kh + qkBase + (size_t)kt * 64 * 64;
        short8 kb[2][4];
#pragma unroll
        for (int ks = 0; ks < 2; ++ks)
#pragma unroll
            for (int ns = 0; ns < 4; ++ns)
                kb[ks][ns] = *(const short8*)(kb_base + (size_t)(ns * 16 + l16) * 64 + ks * 32 + quad * 8);
        // V fragments issued early: latency hides under QK mfmas + exp/store section
        short8 vb[2][4];
#pragma unroll
        for (int ks = 0; ks < 2; ++ks)
#pragma unroll
            for (int ds = 0; ds < 4; ++ds)
                vb[ks][ds] = *(const short8*)(Vt + qkBase + (size_t)(ds * 16 + l16) * 2048 + kt * 64 + ks * 32 + quad * 8);
        floatx4 s[4];
#pragma unroll
        for (int ns = 0; ns < 4; ++ns) s[ns] = (floatx4){0.f, 0.f, 0.f, 0.f};
#pragma unroll
        for (int ks = 0; ks < 2; ++ks)
#pragma unroll
            for (int ns = 0; ns < 4; ++ns)
                s[ns] = __builtin_amdgcn_mfma_f32_16x16x32_bf16(aq[ks], kb[ks][ns], s[ns], 0, 0, 0);

        const size_t prowbase = ((size_t)bh * SEQL + qt * 64 + w * 16) * SEQL + kt * 64;
#pragma unroll
        for (int ns = 0; ns < 4; ++ns) {
#pragma unroll
            for (int r = 0; r < 4; ++r) {
                float p = exp2f(s[ns][r] * EXPSCALE) * inv_l[r];
                int lr16 = quad * 4 + r;
                __builtin_nontemporal_store(p, &P[prowbase + (size_t)lr16 * SEQL + ns * 16 + l16]);
                int col = ns * 16 + l16;
                Ps[(col >> 5) * 2048 + (w * 16 + lr16) * 32 + (col & 31)] = f2bf(p);
            }
        }
        // wave-local LDS exchange: only need lgkmcnt drain, no s_barrier.
        asm volatile("s_waitcnt lgkmcnt(0)" ::: "memory");
        __builtin_amdgcn_sched_barrier(0);
#pragma unroll
        for (int ks = 0; ks < 2; ++ks) {
            short8 pa = *(const short8*)&Ps[ks * 2048 + (w * 16 + l16) * 32 + quad * 8];
#pragma unroll
            for (int ds = 0; ds < 4; ++ds)
                oacc[ds] = __builtin_amdgcn_mfma_f32_16x16x32_bf16(pa, vb[ks][ds], oacc[ds], 0, 0, 0);
        }
    }

    // epilogue: O -> Ows [b*2048+q][h*64+d] bf16
    const int b = bh >> 4, h = bh & 15;
#pragma unroll
    for (int ds = 0; ds < 4; ++ds) {
        int d = h * 64 + ds * 16 + l16;
#pragma unroll
        for (int r = 0; r < 4; ++r) {
            int q = qt * 64 + w * 16 + quad * 4 + r;
            Ows[(size_t)(b * 2048 + q) * 1024 + d] = f2bf(oacc[ds][r]);
        }
    }
}

extern "C" void kernel_launch(void* const* d_in, const int* in_sizes, int n_in,
                              void* d_out, int out_size, void* d_ws, size_t ws_size,
                              hipStream_t stream) {
    const float* query = (const float*)d_in[0];
    const float* key   = (const float*)d_in[1];
    const float* value = (const float*)d_in[2];
    const float* Wq = (const float*)d_in[3];
    const float* bq = (const float*)d_in[4];
    const float* Wk = (const float*)d_in[5];
    const float* bk = (const float*)d_in[6];
    const float* Wv = (const float*)d_in[7];
    const float* bv = (const float*)d_in[8];
    const float* Wo = (const float*)d_in[9];
    const float* bo = (const float*)d_in[10];

    float* out0  = (float*)d_out;                 // [2,2048,1024]
    float* attnW = out0 + (size_t)MROWS * DMODEL; // [2,16,2048,2048]

    short* ws  = (short*)d_ws;
    short* xq  = ws;                      // 4194304
    short* xk  = xq + 4194304;
    short* xv  = xk + 4194304;
    short* wqb = xv + 4194304;            // 1048576 each
    short* wkb = wqb + 1048576;
    short* wvb = wkb + 1048576;
    short* wob = wvb + 1048576;
    short* qh  = wob + 1048576;           // 4194304 each
    short* kh  = qh + 4194304;
    short* vt  = kh + 4194304;
    short* ows = vt + 4194304;

    // converts
    cvt_bf16<<<4096, 256, 0, stream>>>(query, xq, 1048576);
    cvt_bf16<<<4096, 256, 0, stream>>>(key,   xk, 1048576);
    cvt_bf16<<<4096, 256, 0, stream>>>(value, xv, 1048576);
    cvt_bf16<<<1024, 256, 0, stream>>>(Wq, wqb, 262144);
    cvt_bf16<<<1024, 256, 0, stream>>>(Wk, wkb, 262144);
    cvt_bf16<<<1024, 256, 0, stream>>>(Wv, wvb, 262144);
    cvt_bf16<<<1024, 256, 0, stream>>>(Wo, wob, 262144);

    dim3 gg(8, 32);  // N/128, M/128
    gemm_bt<0><<<gg, 256, 0, stream>>>(xq, wqb, bq, qh);
    gemm_bt<0><<<gg, 256, 0, stream>>>(xk, wkb, bk, kh);
    gemm_bt<1><<<gg, 256, 0, stream>>>(xv, wvb, bv, vt);

    attn_kernel<<<dim3(32, 32), 256, 0, stream>>>(qh, kh, vt, attnW, ows);

    gemm_bt<2><<<gg, 256, 0, stream>>>(ows, wob, bo, out0);
}

// Round 2
// 765.050 us; speedup vs baseline: 1.2538x; 1.2538x over previous
//
#include <hip/hip_runtime.h>
#include <hip/hip_bf16.h>
#include <math.h>

#define NHEAD 16
#define DK 64
#define SEQL 2048
#define NBATCH 2
#define DMODEL 1024
#define MROWS 4096   // NBATCH*SEQL

typedef __attribute__((ext_vector_type(4))) float floatx4;
typedef __attribute__((ext_vector_type(8))) short short8;
typedef __attribute__((ext_vector_type(4))) short short4v;

__device__ __forceinline__ short f2bf(float f) {
    __hip_bfloat16 h = __float2bfloat16(f);
    return *reinterpret_cast<short*>(&h);
}

__device__ __forceinline__ void gll16(const void* g, void* l) {
    __builtin_amdgcn_global_load_lds(
        (const __attribute__((address_space(1))) void*)g,
        (__attribute__((address_space(3))) void*)l, 16, 0, 0);
}

// ---------------- fused fp32 -> bf16 convert (all 7 tensors, one launch) ----------------
// layout: [q 1M][k 1M][v 1M][wq 256K][wk 256K][wv 256K][wo 256K] float4-groups
__global__ void cvt_all(const float* __restrict__ q, const float* __restrict__ k,
                        const float* __restrict__ v, const float* __restrict__ wq,
                        const float* __restrict__ wk, const float* __restrict__ wv,
                        const float* __restrict__ wo,
                        short* __restrict__ xq, short* __restrict__ xk, short* __restrict__ xv,
                        short* __restrict__ wqb, short* __restrict__ wkb,
                        short* __restrict__ wvb, short* __restrict__ wob) {
    int i = blockIdx.x * 256 + threadIdx.x;   // 0 .. 4194303
    const float* in; short* out; int j;
    if (i < 3145728) {
        int sel = i >> 20; j = i & 1048575;
        in  = sel == 0 ? q  : (sel == 1 ? k  : v);
        out = sel == 0 ? xq : (sel == 1 ? xk : xv);
    } else {
        int i2 = i - 3145728;
        int sel = i2 >> 18; j = i2 & 262143;
        in  = sel == 0 ? wq  : (sel == 1 ? wk  : (sel == 2 ? wv  : wo));
        out = sel == 0 ? wqb : (sel == 1 ? wkb : (sel == 2 ? wvb : wob));
    }
    float4 f = ((const float4*)in)[j];
    short4v o;
    o.x = f2bf(f.x); o.y = f2bf(f.y); o.z = f2bf(f.z); o.w = f2bf(f.w);
    ((short4v*)out)[j] = o;
}

// ---------------- GEMM body: C[m,n] = sum_k A[m,k]*W[n,k] + bias[n] ----------------
// A: [MROWS,1024] bf16 row-major; W: [1024,1024] bf16 (n,k)
// mode 0: bf16 -> [((b*16+h)*2048+l)*64 + d]
// mode 1: bf16 -> [((b*16+h)*64+d)*2048 + l]
// mode 2: fp32 -> [m*1024 + n]
// XCD swizzle: each XCD owns a contiguous 512-row A chunk across all N (W L2-resident per XCD).
__device__ __forceinline__ void gemm_body(const short* __restrict__ A, const short* __restrict__ W,
                                          const float* __restrict__ bias, void* __restrict__ Out,
                                          int mode, short* As, short* Bs) {
    const int t = threadIdx.x;
    const int lane = t & 63;
    const int w = t >> 6;
    const int wr = w >> 1, wc = w & 1;
    const int quad = lane >> 4;
    const int l16 = lane & 15;
    const int flat = blockIdx.y * 8 + blockIdx.x;          // 0..255, x fastest
    const int bm = ((flat & 7) * 4 + ((flat >> 3) & 3)) * 128;   // XCD-chunked rows
    const int bn = (flat >> 5) * 128;

    floatx4 acc[4][4];
#pragma unroll
    for (int i = 0; i < 4; ++i)
#pragma unroll
        for (int j = 0; j < 4; ++j) acc[i][j] = (floatx4){0.f, 0.f, 0.f, 0.f};

    for (int k0 = 0; k0 < 1024; k0 += 32) {
        __syncthreads();
#pragma unroll
        for (int i = 0; i < 2; ++i) {
            int c = i * 256 + t;
            int row = c >> 2, kk = (c & 3) * 8;
            gll16(A + (size_t)(bm + row) * 1024 + k0 + kk, (char*)As + c * 16);
            gll16(W + (size_t)(bn + row) * 1024 + k0 + kk, (char*)Bs + c * 16);
        }
        __syncthreads();
        short8 af[4], bfr[4];
#pragma unroll
        for (int ms = 0; ms < 4; ++ms)
            af[ms] = *(const short8*)&As[(wr * 64 + ms * 16 + l16) * 32 + quad * 8];
#pragma unroll
        for (int ns = 0; ns < 4; ++ns)
            bfr[ns] = *(const short8*)&Bs[(wc * 64 + ns * 16 + l16) * 32 + quad * 8];
#pragma unroll
        for (int ms = 0; ms < 4; ++ms)
#pragma unroll
            for (int ns = 0; ns < 4; ++ns)
                acc[ms][ns] = __builtin_amdgcn_mfma_f32_16x16x32_bf16(
                    af[ms], bfr[ns], acc[ms][ns], 0, 0, 0);
    }

#pragma unroll
    for (int ms = 0; ms < 4; ++ms) {
#pragma unroll
        for (int ns = 0; ns < 4; ++ns) {
            int n = bn + wc * 64 + ns * 16 + l16;
            float bv = bias[n];
#pragma unroll
            for (int r = 0; r < 4; ++r) {
                int m = bm + wr * 64 + ms * 16 + quad * 4 + r;
                float v = acc[ms][ns][r] + bv;
                if (mode == 2) {
                    ((float*)Out)[(size_t)m * 1024 + n] = v;
                } else {
                    int b = m >> 11, l = m & 2047;
                    int h = n >> 6, d = n & 63;
                    short* o = (short*)Out;
                    if (mode == 0)
                        o[(((size_t)(b * 16 + h) * 2048 + l) * 64) + d] = f2bf(v);
                    else
                        o[(((size_t)(b * 16 + h) * 64 + d) * 2048) + l] = f2bf(v);
                }
            }
        }
    }
}

// fused Q/K/V projection: grid (8,32,3) = 768 blocks = 3 blocks/CU
__global__ __launch_bounds__(256, 3)
void qkv_gemm(const short* __restrict__ xq, const short* __restrict__ xk,
              const short* __restrict__ xv, const short* __restrict__ wqb,
              const short* __restrict__ wkb, const short* __restrict__ wvb,
              const float* __restrict__ bq, const float* __restrict__ bk,
              const float* __restrict__ bv,
              short* __restrict__ qh, short* __restrict__ kh, short* __restrict__ vt) {
    __shared__ __align__(16) short As[128 * 32];
    __shared__ __align__(16) short Bs[128 * 32];
    const int z = blockIdx.z;
    const short* A = z == 0 ? xq : (z == 1 ? xk : xv);
    const short* W = z == 0 ? wqb : (z == 1 ? wkb : wvb);
    const float* bias = z == 0 ? bq : (z == 1 ? bk : bv);
    void* Out = z == 0 ? (void*)qh : (z == 1 ? (void*)kh : (void*)vt);
    gemm_body(A, W, bias, Out, z == 2 ? 1 : 0, As, Bs);
}

__global__ __launch_bounds__(256, 2)
void out_gemm(const short* __restrict__ ows, const short* __restrict__ wob,
              const float* __restrict__ bo, float* __restrict__ out0) {
    __shared__ __align__(16) short As[128 * 32];
    __shared__ __align__(16) short Bs[128 * 32];
    gemm_body(ows, wob, bo, (void*)out0, 2, As, Bs);
}

// ---------------- attention: per (q-tile 64, bh) block ----------------
// Qh,Kh: [BH, L, 64] bf16 ; Vt: [BH, 64, L] bf16
// P (fp32) -> attnW [BH, L, L]; O (bf16) -> Ows [B*L, 1024]
// LDS-staged K/V (broadcast to 4 waves), double-buffered; no-max softmax
// (|scores| <~ 10 << 88 in fp32); wave-local Ps exchange (lgkm-only).
// Pass-2 barrier is counted vmcnt(16): P stores stay in flight across it.
#define EXPSCALE 0.18033688f   // 0.125 * log2(e)
__global__ __launch_bounds__(256, 4)
void attn_kernel(const short* __restrict__ Qh, const short* __restrict__ Kh,
                 const short* __restrict__ Vt, float* __restrict__ P,
                 short* __restrict__ Ows) {
    __shared__ __align__(16) short Ks[2][4096];   // 2 x 8KB  [ks][row][32]
    __shared__ __align__(16) short Vs[2][4096];   // 2 x 8KB
    __shared__ __align__(16) short Ps[4096];      // 8KB, wave-local rows

    const int t = threadIdx.x;
    const int lane = t & 63;
    const int w = t >> 6;
    const int quad = lane >> 4;
    const int l16 = lane & 15;
    // XCD-bijective swizzle: XCD x owns bh in {x, x+8, x+16, x+24}, all 32 q-tiles.
    const int flat = blockIdx.y * 32 + blockIdx.x;
    const int bh = (flat & 7) + 8 * (flat >> 8);
    const int qt = (flat >> 3) & 31;
    const size_t qkBase = (size_t)bh * SEQL * DK;

    // Q fragments direct from global (one 16-row slab per wave)
    short8 aq[2];
    {
        const short* qrow = Qh + qkBase + (size_t)(qt * 64 + w * 16 + l16) * 64;
        aq[0] = *(const short8*)(qrow + quad * 8);
        aq[1] = *(const short8*)(qrow + 32 + quad * 8);
    }

    // ---- pass 1: per-lane partial exp-sums, double-buffered K staging ----
#pragma unroll
    for (int i = 0; i < 2; ++i) {
        int c = i * 256 + t;
        int ks = c >> 8, r = (c >> 2) & 63, c4 = c & 3;
        gll16(Kh + qkBase + (size_t)r * 64 + ks * 32 + c4 * 8, (char*)&Ks[0][0] + c * 16);
    }
    __syncthreads();

    float psum[4] = {0.f, 0.f, 0.f, 0.f};
#pragma unroll 2
    for (int kt = 0; kt < 32; ++kt) {
        const int cur = kt & 1;
        if (kt < 31) {
#pragma unroll
            for (int i = 0; i < 2; ++i) {
                int c = i * 256 + t;
                int ks = c >> 8, r = (c >> 2) & 63, c4 = c & 3;
                gll16(Kh + qkBase + (size_t)((kt + 1) * 64 + r) * 64 + ks * 32 + c4 * 8,
                      (char*)&Ks[cur ^ 1][0] + c * 16);
            }
        }
        __builtin_amdgcn_sched_barrier(0);
        floatx4 s[4];
#pragma unroll
        for (int ns = 0; ns < 4; ++ns) s[ns] = (floatx4){0.f, 0.f, 0.f, 0.f};
#pragma unroll
        for (int ks = 0; ks < 2; ++ks)
#pragma unroll
            for (int ns = 0; ns < 4; ++ns) {
                short8 kb = *(const short8*)&Ks[cur][ks * 2048 + (ns * 16 + l16) * 32 + quad * 8];
                s[ns] = __builtin_amdgcn_mfma_f32_16x16x32_bf16(aq[ks], kb, s[ns], 0, 0, 0);
            }
#pragma unroll
        for (int ns = 0; ns < 4; ++ns)
#pragma unroll
            for (int r = 0; r < 4; ++r)
                psum[r] += exp2f(s[ns][r] * EXPSCALE);
        if (kt < 31) __syncthreads();
    }
    // one reduce across the 16-lane column group (rows are per (w,quad,r))
#pragma unroll
    for (int off = 1; off < 16; off <<= 1)
#pragma unroll
        for (int r = 0; r < 4; ++r)
            psum[r] += __shfl_xor(psum[r], off, 64);
    float inv_l[4];
#pragma unroll
    for (int r = 0; r < 4; ++r) inv_l[r] = 1.f / psum[r];

    floatx4 oacc[4];
#pragma unroll
    for (int i = 0; i < 4; ++i) oacc[i] = (floatx4){0.f, 0.f, 0.f, 0.f};

    // ---- pass 2: recompute S, write P, accumulate O; K+V double-buffered ----
#pragma unroll
    for (int i = 0; i < 2; ++i) {
        int c = i * 256 + t;
        int ks = c >> 8, r = (c >> 2) & 63, c4 = c & 3;
        gll16(Kh + qkBase + (size_t)r * 64 + ks * 32 + c4 * 8, (char*)&Ks[0][0] + c * 16);
        gll16(Vt + qkBase + (size_t)r * 2048 + ks * 32 + c4 * 8, (char*)&Vs[0][0] + c * 16);
    }
    __syncthreads();

#pragma unroll 2
    for (int kt = 0; kt < 32; ++kt) {
        const int cur = kt & 1;
        if (kt < 31) {
#pragma unroll
            for (int i = 0; i < 2; ++i) {
                int c = i * 256 + t;
                int ks = c >> 8, r = (c >> 2) & 63, c4 = c & 3;
                gll16(Kh + qkBase + (size_t)((kt + 1) * 64 + r) * 64 + ks * 32 + c4 * 8,
                      (char*)&Ks[cur ^ 1][0] + c * 16);
                gll16(Vt + qkBase + (size_t)r * 2048 + (kt + 1) * 64 + ks * 32 + c4 * 8,
                      (char*)&Vs[cur ^ 1][0] + c * 16);
            }
        }
        __builtin_amdgcn_sched_barrier(0);   // pin: staging issues before stores

        floatx4 s[4];
#pragma unroll
        for (int ns = 0; ns < 4; ++ns) s[ns] = (floatx4){0.f, 0.f, 0.f, 0.f};
#pragma unroll
        for (int ks = 0; ks < 2; ++ks)
#pragma unroll
            for (int ns = 0; ns < 4; ++ns) {
                short8 kb = *(const short8*)&Ks[cur][ks * 2048 + (ns * 16 + l16) * 32 + quad * 8];
                s[ns] = __builtin_amdgcn_mfma_f32_16x16x32_bf16(aq[ks], kb, s[ns], 0, 0, 0);
            }
        // V fragments early (LDS latency hides under exp/store section)
        short8 vb[2][4];
#pragma unroll
        for (int ks = 0; ks < 2; ++ks)
#pragma unroll
            for (int ds = 0; ds < 4; ++ds)
                vb[ks][ds] = *(const short8*)&Vs[cur][ks * 2048 + (ds * 16 + l16) * 32 + quad * 8];

        const size_t prowbase = ((size_t)bh * SEQL + qt * 64 + w * 16) * SEQL + kt * 64;
#pragma unroll
        for (int ns = 0; ns < 4; ++ns) {
#pragma unroll
            for (int r = 0; r < 4; ++r) {
                float p = exp2f(s[ns][r] * EXPSCALE) * inv_l[r];
                int lr16 = quad * 4 + r;
                P[prowbase + (size_t)lr16 * SEQL + ns * 16 + l16] = p;
                int col = ns * 16 + l16;
                Ps[(col >> 5) * 2048 + (w * 16 + lr16) * 32 + (col & 31)] = f2bf(p);
            }
        }
        // wave-local Ps exchange: lgkm drain only, no barrier
        asm volatile("s_waitcnt lgkmcnt(0)" ::: "memory");
        __builtin_amdgcn_sched_barrier(0);
#pragma unroll
        for (int ks = 0; ks < 2; ++ks) {
            short8 pa = *(const short8*)&Ps[ks * 2048 + (w * 16 + l16) * 32 + quad * 8];
#pragma unroll
            for (int ds = 0; ds < 4; ++ds)
                oacc[ds] = __builtin_amdgcn_mfma_f32_16x16x32_bf16(pa, vb[ks][ds], oacc[ds], 0, 0, 0);
        }
        if (kt < 31) {
            // counted drain: waits the 4 staging loads (older), leaves the
            // 16 newest vmem ops (the P stores) in flight across the barrier
            asm volatile("s_waitcnt vmcnt(16)" ::: "memory");
            __builtin_amdgcn_s_barrier();
        }
    }

    // epilogue: O -> Ows [b*2048+q][h*64+d] bf16
    const int b = bh >> 4, h = bh & 15;
#pragma unroll
    for (int ds = 0; ds < 4; ++ds) {
        int d = h * 64 + ds * 16 + l16;
#pragma unroll
        for (int r = 0; r < 4; ++r) {
            int q = qt * 64 + w * 16 + quad * 4 + r;
            Ows[(size_t)(b * 2048 + q) * 1024 + d] = f2bf(oacc[ds][r]);
        }
    }
}

extern "C" void kernel_launch(void* const* d_in, const int* in_sizes, int n_in,
                              void* d_out, int out_size, void* d_ws, size_t ws_size,
                              hipStream_t stream) {
    const float* query = (const float*)d_in[0];
    const float* key   = (const float*)d_in[1];
    const float* value = (const float*)d_in[2];
    const float* Wq = (const float*)d_in[3];
    const float* bq = (const float*)d_in[4];
    const float* Wk = (const float*)d_in[5];
    const float* bk = (const float*)d_in[6];
    const float* Wv = (const float*)d_in[7];
    const float* bv = (const float*)d_in[8];
    const float* Wo = (const float*)d_in[9];
    const float* bo = (const float*)d_in[10];

    float* out0  = (float*)d_out;                 // [2,2048,1024]
    float* attnW = out0 + (size_t)MROWS * DMODEL; // [2,16,2048,2048]

    short* ws  = (short*)d_ws;
    short* xq  = ws;                      // 4194304
    short* xk  = xq + 4194304;
    short* xv  = xk + 4194304;
    short* wqb = xv + 4194304;            // 1048576 each
    short* wkb = wqb + 1048576;
    short* wvb = wkb + 1048576;
    short* wob = wvb + 1048576;
    short* qh  = wob + 1048576;           // 4194304 each
    short* kh  = qh + 4194304;
    short* vt  = kh + 4194304;
    short* ows = vt + 4194304;

    cvt_all<<<16384, 256, 0, stream>>>(query, key, value, Wq, Wk, Wv, Wo,
                                       xq, xk, xv, wqb, wkb, wvb, wob);

    qkv_gemm<<<dim3(8, 32, 3), 256, 0, stream>>>(xq, xk, xv, wqb, wkb, wvb,
                                                 bq, bk, bv, qh, kh, vt);

    attn_kernel<<<dim3(32, 32), 256, 0, stream>>>(qh, kh, vt, attnW, ows);

    out_gemm<<<dim3(8, 32), 256, 0, stream>>>(ows, wob, bo, out0);
}